// Round 2
// baseline (438.796 us; speedup 1.0000x reference)
//
#include <hip/hip_runtime.h>

// Problem constants
#define BB 4
#define NN 1024
#define FF 512
#define HH 8
#define DD 64
#define EE 16

typedef unsigned short u16;
typedef __attribute__((ext_vector_type(8))) short     bf16x8;
typedef __attribute__((ext_vector_type(8))) unsigned short u16x8;
typedef __attribute__((ext_vector_type(4))) float     f32x4;

#define MFMA(a,b,c) __builtin_amdgcn_mfma_f32_16x16x32_bf16((a),(b),(c),0,0,0)

static __device__ __forceinline__ u16 f2bf(float f){
  unsigned u = __float_as_uint(f);
  unsigned r = (u + 0x7FFFu + ((u >> 16) & 1u)) >> 16;   // RNE
  return (u16)r;
}
static __device__ __forceinline__ float bf2f(u16 h){
  return __uint_as_float(((unsigned)h) << 16);
}
static __device__ __forceinline__ void gld16(const void* g, void* l){
  __builtin_amdgcn_global_load_lds((const __attribute__((address_space(1))) unsigned int*)g,
                                   (__attribute__((address_space(3))) unsigned int*)l, 16, 0, 0);
}

// ---------------------------------------------------------------------------
// K0: transpose + hi/lo-split weights.
__global__ __launch_bounds__(256) void k_wsplit(
    const float* __restrict__ Wq, const float* __restrict__ Wk,
    const float* __restrict__ Wv, const float* __restrict__ Wo,
    u16* __restrict__ WhT, u16* __restrict__ WlT, u16* __restrict__ WoT){
  __shared__ float tile[32][33];
  int bid = blockIdx.x, t = threadIdx.x;
  int isA = bid < 768;
  int tb  = isA ? bid : bid - 768;
  int nct = isA ? 48 : 16;
  int ct = tb % nct, ft = tb / nct;
  int c0 = ct * 32, f0 = ft * 32;
  #pragma unroll
  for (int r4 = 0; r4 < 4; r4++){
    int fl = (t >> 5) * 4 + r4, cl = t & 31;
    int f = f0 + fl, c = c0 + cl;
    float v;
    if (isA){
      const float* W = (c < 512) ? Wq : ((c < 1024) ? Wk : Wv);
      v = W[f * 512 + (c & 511)];
    } else {
      v = Wo[f * 512 + c];
    }
    tile[fl][cl] = v;
  }
  __syncthreads();
  #pragma unroll
  for (int r4 = 0; r4 < 4; r4++){
    int cl = (t >> 5) * 4 + r4, fl = t & 31;
    float v = tile[fl][cl];
    int c = c0 + cl, f = f0 + fl;
    if (isA){
      u16 hi = f2bf(v);
      WhT[c * 512 + f] = hi;
      WlT[c * 512 + f] = f2bf(v - bf2f(hi));
    } else {
      WoT[c * 512 + f] = f2bf(v);
    }
  }
}

// ---------------------------------------------------------------------------
// K1: LayerNorm (fp32) -> r split into hi/lo bf16. One wave per row.
__global__ __launch_bounds__(256) void k_ln(
    const float* __restrict__ x, const float* __restrict__ gamma,
    const float* __restrict__ beta, u16* __restrict__ rh, u16* __restrict__ rl){
  int row  = blockIdx.x * 4 + (threadIdx.x >> 6);
  int lane = threadIdx.x & 63;
  const float* px = x + (size_t)row * 512 + lane * 8;
  float4 a = *(const float4*)px;
  float4 b = *(const float4*)(px + 4);
  float v[8] = {a.x,a.y,a.z,a.w,b.x,b.y,b.z,b.w};
  float s = 0.f, q = 0.f;
  #pragma unroll
  for (int j = 0; j < 8; j++){ s += v[j]; q += v[j]*v[j]; }
  #pragma unroll
  for (int m = 1; m < 64; m <<= 1){ s += __shfl_xor(s, m, 64); q += __shfl_xor(q, m, 64); }
  float mean = s * (1.f/512.f);
  float var  = q * (1.f/512.f) - mean * mean;
  float rstd = rsqrtf(var + 1e-5f);
  float4 ga = *(const float4*)(gamma + lane*8);
  float4 gb = *(const float4*)(gamma + lane*8 + 4);
  float4 b0 = *(const float4*)(beta  + lane*8);
  float4 b1 = *(const float4*)(beta  + lane*8 + 4);
  float gs[8] = {ga.x,ga.y,ga.z,ga.w,gb.x,gb.y,gb.z,gb.w};
  float bs[8] = {b0.x,b0.y,b0.z,b0.w,b1.x,b1.y,b1.z,b1.w};
  u16x8 hv, lv;
  #pragma unroll
  for (int j = 0; j < 8; j++){
    float r = (v[j] - mean) * rstd * gs[j] + bs[j];
    u16 hi = f2bf(r);
    hv[j] = hi;
    lv[j] = f2bf(r - bf2f(hi));
  }
  *(u16x8*)(rh + (size_t)row * 512 + lane * 8) = hv;
  *(u16x8*)(rl + (size_t)row * 512 + lane * 8) = lv;
}

// ---------------------------------------------------------------------------
// K2: QKV projection GEMM, split-3, 128x128 tile BK=32 (unchanged).
__global__ __launch_bounds__(256) void k_qkv(
    const u16* __restrict__ rh, const u16* __restrict__ rl,
    const u16* __restrict__ WhT, const u16* __restrict__ WlT,
    u16* __restrict__ qh, u16* __restrict__ ql,
    u16* __restrict__ kh, u16* __restrict__ kl, u16* __restrict__ vT){
  __shared__ u16 Ah[128*32], Al[128*32], Bh[128*32], Bl[128*32];
  int bid = blockIdx.x;
  int mt = bid & 31, nt = bid >> 5;
  int m0 = mt << 7,  n0 = nt << 7;
  int t = threadIdx.x, lane = t & 63, w = t >> 6;
  int wm = (w >> 1) << 6, wn = (w & 1) << 6;
  int fr = lane & 15, g = lane >> 4;
  f32x4 acc[4][4];
  #pragma unroll
  for (int i = 0; i < 4; i++)
    #pragma unroll
    for (int j = 0; j < 4; j++) acc[i][j] = (f32x4){0.f,0.f,0.f,0.f};

  for (int k0 = 0; k0 < 512; k0 += 32){
    #pragma unroll
    for (int q = 0; q < 2; q++){
      int c = ((q << 2) + w) * 64 + lane;
      int row = c >> 2, part = c & 3;
      int ldso = ((q << 2) + w) * 512;
      gld16(rh  + (size_t)(m0+row)*512 + k0 + part*8, &Ah[ldso]);
      gld16(rl  + (size_t)(m0+row)*512 + k0 + part*8, &Al[ldso]);
      gld16(WhT + (size_t)(n0+row)*512 + k0 + part*8, &Bh[ldso]);
      gld16(WlT + (size_t)(n0+row)*512 + k0 + part*8, &Bl[ldso]);
    }
    __syncthreads();
    bf16x8 a_h[4], a_l[4], b_h[4], b_l[4];
    #pragma unroll
    for (int mi = 0; mi < 4; mi++){
      int off = (wm + mi*16 + fr)*32 + g*8;
      a_h[mi] = *(const bf16x8*)&Ah[off];
      a_l[mi] = *(const bf16x8*)&Al[off];
    }
    #pragma unroll
    for (int ni = 0; ni < 4; ni++){
      int off = (wn + ni*16 + fr)*32 + g*8;
      b_h[ni] = *(const bf16x8*)&Bh[off];
      b_l[ni] = *(const bf16x8*)&Bl[off];
    }
    #pragma unroll
    for (int mi = 0; mi < 4; mi++)
      #pragma unroll
      for (int ni = 0; ni < 4; ni++){
        acc[mi][ni] = MFMA(a_h[mi], b_h[ni], acc[mi][ni]);
        acc[mi][ni] = MFMA(a_h[mi], b_l[ni], acc[mi][ni]);
        acc[mi][ni] = MFMA(a_l[mi], b_h[ni], acc[mi][ni]);
      }
    __syncthreads();
  }
  #pragma unroll
  for (int mi = 0; mi < 4; mi++)
    #pragma unroll
    for (int ni = 0; ni < 4; ni++)
      #pragma unroll
      for (int r = 0; r < 4; r++){
        int gm = m0 + wm + mi*16 + g*4 + r;
        int gc = n0 + wn + ni*16 + fr;
        float vv = acc[mi][ni][r];
        int b = gm >> 10, i = gm & 1023;
        int mat = gc >> 9, h = (gc >> 6) & 7, d = gc & 63;
        size_t idx = ((size_t)((b << 3) + h) * 1024 + i) * 64 + d;
        if (mat == 0){
          u16 hi = f2bf(vv); qh[idx] = hi; ql[idx] = f2bf(vv - bf2f(hi));
        } else if (mat == 1){
          u16 hi = f2bf(vv); kh[idx] = hi; kl[idx] = f2bf(vv - bf2f(hi));
        } else {
          vT[((size_t)((b << 3) + h) * 64 + d) * 1024 + i] = f2bf(vv);
        }
      }
}

// ---------------------------------------------------------------------------
// K3: fused attention, j-split 4-way. 1024 blocks = (b, i-tile of 16, s).
// Each block handles j in [s*256, s*256+256) with online softmax, emits
// partial (o/den bf16, m, den) for combine.
__global__ __launch_bounds__(512, 6) void k_attn(
    const float* __restrict__ edge, const float* __restrict__ mask,
    const float* __restrict__ We,
    const u16* __restrict__ qh, const u16* __restrict__ ql,
    const u16* __restrict__ kh, const u16* __restrict__ kl,
    const u16* __restrict__ vT, u16* __restrict__ part_o,
    float2* __restrict__ part_md){
  __shared__ float We_s[128];                 // [e][h]
  __shared__ float bias_s[8][16*33];          // [h][i*33+j]
  __shared__ float mask_s[16*33];             // [i*33+j]
  __shared__ u16   pm_s[8][16*40];            // per-wave [i][40] bf16

  int bid = blockIdx.x;
  int s  = bid & 3;
  int i0 = ((bid >> 2) & 63) << 4;
  int b  = bid >> 8;
  int t = threadIdx.x, lane = t & 63, w = t >> 6;   // w = head
  int fr = lane & 15, g = lane >> 4;
  if (t < 128) We_s[t] = We[t];

  // Q fragments (rows i0..i0+15, all 64 d), hi/lo
  size_t qb = ((size_t)((b << 3) + w) * 1024 + i0 + fr) * 64 + g * 8;
  bf16x8 qfh0 = *(const bf16x8*)(qh + qb);
  bf16x8 qfh1 = *(const bf16x8*)(qh + qb + 32);
  bf16x8 qfl0 = *(const bf16x8*)(ql + qb);
  bf16x8 qfl1 = *(const bf16x8*)(ql + qb + 32);

  f32x4 oacc[4];
  #pragma unroll
  for (int vf = 0; vf < 4; vf++) oacc[vf] = (f32x4){0.f,0.f,0.f,0.f};
  float mrun[4], den[4];
  #pragma unroll
  for (int r = 0; r < 4; r++){ mrun[r] = -3e38f; den[r] = 0.f; }

  int pi = t >> 5, pj = t & 31;               // this thread's (i,j) pair for bias
  const float* ebase = edge + ((size_t)(b*1024 + i0 + pi) * 1024 + s*256 + pj) * 16;
  const float* mbase = mask + (size_t)(b*1024 + i0 + pi) * 1024 + s*256 + pj;
  __syncthreads();

  // prologue: edge+mask for tile 0 of this split
  float4 e0 = *(const float4*)(ebase);
  float4 e1 = *(const float4*)(ebase + 4);
  float4 e2 = *(const float4*)(ebase + 8);
  float4 e3 = *(const float4*)(ebase + 12);
  float  mval = *mbase;

  #pragma unroll 1
  for (int jt = 0; jt < 8; jt++){
    int j0 = s*256 + (jt << 5);
    float ef[16] = {e0.x,e0.y,e0.z,e0.w, e1.x,e1.y,e1.z,e1.w,
                    e2.x,e2.y,e2.z,e2.w, e3.x,e3.y,e3.z,e3.w};
    float bias[8] = {0.f,0.f,0.f,0.f,0.f,0.f,0.f,0.f};
    #pragma unroll
    for (int e = 0; e < 16; e++){
      float ev = ef[e];
      #pragma unroll
      for (int h = 0; h < 8; h++) bias[h] += ev * We_s[e*8 + h];
    }
    #pragma unroll
    for (int h = 0; h < 8; h++) bias_s[h][pi*33 + pj] = bias[h];
    mask_s[pi*33 + pj] = mval;
    __syncthreads();

    // prefetch next tile's edge (drains at end-of-loop barrier, overlapped)
    if (jt < 7){
      const float* ep = ebase + (size_t)((jt + 1) << 5) * 16;
      e0 = *(const float4*)(ep);
      e1 = *(const float4*)(ep + 4);
      e2 = *(const float4*)(ep + 8);
      e3 = *(const float4*)(ep + 12);
      mval = mbase[(jt + 1) << 5];
    }

    // K fragments for this head (j0..j0+31, hi/lo)
    size_t kb0 = ((size_t)((b << 3) + w) * 1024 + j0 + fr) * 64 + g * 8;
    size_t kb1 = kb0 + 16 * 64;
    bf16x8 kfh00 = *(const bf16x8*)(kh + kb0);
    bf16x8 kfh01 = *(const bf16x8*)(kh + kb0 + 32);
    bf16x8 kfh10 = *(const bf16x8*)(kh + kb1);
    bf16x8 kfh11 = *(const bf16x8*)(kh + kb1 + 32);
    bf16x8 kfl00 = *(const bf16x8*)(kl + kb0);
    bf16x8 kfl01 = *(const bf16x8*)(kl + kb0 + 32);
    bf16x8 kfl10 = *(const bf16x8*)(kl + kb1);
    bf16x8 kfl11 = *(const bf16x8*)(kl + kb1 + 32);

    f32x4 lg0 = (f32x4){0.f,0.f,0.f,0.f};
    f32x4 lg1 = (f32x4){0.f,0.f,0.f,0.f};
    // interleave the two independent accumulator chains
    lg0 = MFMA(qfh0, kfh00, lg0); lg1 = MFMA(qfh0, kfh10, lg1);
    lg0 = MFMA(qfh1, kfh01, lg0); lg1 = MFMA(qfh1, kfh11, lg1);
    lg0 = MFMA(qfh0, kfl00, lg0); lg1 = MFMA(qfh0, kfl10, lg1);
    lg0 = MFMA(qfh1, kfl01, lg0); lg1 = MFMA(qfh1, kfl11, lg1);
    lg0 = MFMA(qfl0, kfh00, lg0); lg1 = MFMA(qfl0, kfh10, lg1);
    lg0 = MFMA(qfl1, kfh01, lg0); lg1 = MFMA(qfl1, kfh11, lg1);

    float tm[4];
    #pragma unroll
    for (int r = 0; r < 4; r++){
      int row = g*4 + r;
      lg0[r] += bias_s[w][row*33 + fr];
      lg1[r] += bias_s[w][row*33 + 16 + fr];
      tm[r] = fmaxf(lg0[r], lg1[r]);
    }
    #pragma unroll
    for (int mk = 1; mk < 16; mk <<= 1){
      #pragma unroll
      for (int r = 0; r < 4; r++) tm[r] = fmaxf(tm[r], __shfl_xor(tm[r], mk, 16));
    }
    float p0[4], p1[4], scl[4], ps[4];
    #pragma unroll
    for (int r = 0; r < 4; r++){
      float nm = fmaxf(mrun[r], tm[r]);
      scl[r] = exp2f((mrun[r] - nm) * 1.44269504089f);
      mrun[r] = nm;
      p0[r] = exp2f((lg0[r] - nm) * 1.44269504089f);
      p1[r] = exp2f((lg1[r] - nm) * 1.44269504089f);
      ps[r] = p0[r] + p1[r];
    }
    #pragma unroll
    for (int mk = 1; mk < 16; mk <<= 1){
      #pragma unroll
      for (int r = 0; r < 4; r++) ps[r] += __shfl_xor(ps[r], mk, 16);
    }
    #pragma unroll
    for (int r = 0; r < 4; r++) den[r] = den[r] * scl[r] + ps[r];
    #pragma unroll
    for (int vf = 0; vf < 4; vf++)
      #pragma unroll
      for (int r = 0; r < 4; r++) oacc[vf][r] *= scl[r];

    // masked P -> bf16 -> LDS (C-layout scatter), then A-frag read
    #pragma unroll
    for (int r = 0; r < 4; r++){
      int row = g*4 + r;
      pm_s[w][row*40 + fr]      = f2bf(p0[r] * mask_s[row*33 + fr]);
      pm_s[w][row*40 + 16 + fr] = f2bf(p1[r] * mask_s[row*33 + 16 + fr]);
    }
    asm volatile("s_waitcnt lgkmcnt(0)" ::: "memory");
    bf16x8 pa = *(const bf16x8*)&pm_s[w][fr*40 + g*8];
    #pragma unroll
    for (int vf = 0; vf < 4; vf++){
      const u16* vp = vT + ((size_t)((b << 3) + w) * 64 + vf*16 + fr) * 1024 + j0 + g*8;
      bf16x8 vfr = *(const bf16x8*)vp;
      oacc[vf] = MFMA(pa, vfr, oacc[vf]);
    }
    __syncthreads();
  }

  // partial store: o/den as bf16, (m, den) fp32
  float id[4];
  #pragma unroll
  for (int r = 0; r < 4; r++) id[r] = 1.0f / den[r];
  int bh = (b << 3) + w;
  #pragma unroll
  for (int vf = 0; vf < 4; vf++)
    #pragma unroll
    for (int r = 0; r < 4; r++){
      int row = g*4 + r;
      part_o[((size_t)((s*32 + bh) * 1024) + i0 + row) * 64 + vf*16 + fr] =
          f2bf(oacc[vf][r] * id[r]);
    }
  if (fr == 0){
    #pragma unroll
    for (int r = 0; r < 4; r++){
      int row = g*4 + r;
      part_md[(size_t)(s*32 + bh) * 1024 + i0 + row] = make_float2(mrun[r], den[r]);
    }
  }
}

// ---------------------------------------------------------------------------
// K4: combine the 4 j-split partials -> AO bf16 [b,i][h*64+d].
__global__ __launch_bounds__(256) void k_combine(
    const u16* __restrict__ part_o, const float2* __restrict__ part_md,
    u16* __restrict__ AO){
  int wg   = blockIdx.x * 4 + (threadIdx.x >> 6);   // row id 0..32767
  int lane = threadIdx.x & 63;
  int bh = wg >> 10, i = wg & 1023;
  int b = bh >> 3, h = bh & 7;
  float2 md[4];
  float M = -3e38f;
  #pragma unroll
  for (int s = 0; s < 4; s++){
    md[s] = part_md[(size_t)(s*32 + bh) * 1024 + i];
    M = fmaxf(M, md[s].x);
  }
  float wsum = 0.f, o = 0.f;
  #pragma unroll
  for (int s = 0; s < 4; s++){
    float wq = md[s].y * exp2f((md[s].x - M) * 1.44269504089f);
    wsum += wq;
    o += wq * bf2f(part_o[((size_t)((s*32 + bh) * 1024) + i) * 64 + lane]);
  }
  AO[((size_t)(b*1024 + i)) * 512 + h*64 + lane] = f2bf(o * 0.125f / wsum);
}

// ---------------------------------------------------------------------------
// K5: out = AO @ Wo + residual. Single-pass bf16, 64x128 tile, BK=32.
__global__ __launch_bounds__(256) void k_out(
    const u16* __restrict__ AO, const u16* __restrict__ WoT,
    const float* __restrict__ x, float* __restrict__ out){
  __shared__ u16 As[64*32], Bs[128*32];
  int bid = blockIdx.x;
  int mt = bid & 63, nt = bid >> 6;
  int m0 = mt << 6, n0 = nt << 7;
  int t = threadIdx.x, lane = t & 63, w = t >> 6;
  int wm = (w >> 1) << 5, wn = (w & 1) << 6;
  int fr = lane & 15, g = lane >> 4;
  f32x4 acc[2][4];
  #pragma unroll
  for (int i = 0; i < 2; i++)
    #pragma unroll
    for (int j = 0; j < 4; j++) acc[i][j] = (f32x4){0.f,0.f,0.f,0.f};

  for (int k0 = 0; k0 < 512; k0 += 32){
    {
      int row = t >> 2, part = t & 3;
      gld16(AO + (size_t)(m0+row)*512 + k0 + part*8, &As[w*512]);
    }
    #pragma unroll
    for (int q = 0; q < 2; q++){
      int c = ((q << 2) + w) * 64 + lane;
      int row = c >> 2, part = c & 3;
      gld16(WoT + (size_t)(n0+row)*512 + k0 + part*8, &Bs[((q<<2)+w)*512]);
    }
    __syncthreads();
    bf16x8 af[2], bf_[4];
    #pragma unroll
    for (int mi = 0; mi < 2; mi++) af[mi]  = *(const bf16x8*)&As[(wm + mi*16 + fr)*32 + g*8];
    #pragma unroll
    for (int ni = 0; ni < 4; ni++) bf_[ni] = *(const bf16x8*)&Bs[(wn + ni*16 + fr)*32 + g*8];
    #pragma unroll
    for (int mi = 0; mi < 2; mi++)
      #pragma unroll
      for (int ni = 0; ni < 4; ni++)
        acc[mi][ni] = MFMA(af[mi], bf_[ni], acc[mi][ni]);
    __syncthreads();
  }
  #pragma unroll
  for (int mi = 0; mi < 2; mi++)
    #pragma unroll
    for (int ni = 0; ni < 4; ni++)
      #pragma unroll
      for (int r = 0; r < 4; r++){
        size_t gm = m0 + wm + mi*16 + g*4 + r;
        size_t gn = n0 + wn + ni*16 + fr;
        out[gm*512 + gn] = acc[mi][ni][r] + x[gm*512 + gn];
      }
}

// ---------------------------------------------------------------------------
extern "C" void kernel_launch(void* const* d_in, const int* in_sizes, int n_in,
                              void* d_out, int out_size, void* d_ws, size_t ws_size,
                              hipStream_t stream){
  const float* xin   = (const float*)d_in[0];
  const float* edge  = (const float*)d_in[1];
  const float* mask  = (const float*)d_in[2];
  const float* gamma = (const float*)d_in[3];
  const float* beta  = (const float*)d_in[4];
  const float* Wq    = (const float*)d_in[5];
  const float* Wk    = (const float*)d_in[6];
  const float* Wv    = (const float*)d_in[7];
  const float* We    = (const float*)d_in[8];
  const float* Wo    = (const float*)d_in[9];
  float* out = (float*)d_out;

  u16* p   = (u16*)d_ws;
  u16* WoT = p;                 p += 512*512;      // live until k_out
  u16* qh  = p;                 p += 2097152;
  u16* ql  = p;                 p += 2097152;
  u16* kh  = p;                 p += 2097152;
  u16* kl  = p;                 p += 2097152;
  u16* vT  = p;                 p += 2097152;
  u16* AO  = p;                 p += 2097152;
  // union region: {rh, rl, WhT, WlT} (dead after k_qkv) vs {part_o, part_md}
  u16* U   = p;
  u16* rh  = U;
  u16* rl  = U + 2097152;
  u16* WhT = U + 4194304;
  u16* WlT = U + 4194304 + 786432;
  u16* part_o = U;                                  // 4*32768*64 u16 = 8.39M u16
  float2* part_md = (float2*)(U + 8388608);         // 4*32768 float2

  k_wsplit <<<1024, 256, 0, stream>>>(Wq, Wk, Wv, Wo, WhT, WlT, WoT);
  k_ln     <<<1024, 256, 0, stream>>>(xin, gamma, beta, rh, rl);
  k_qkv    <<<384,  256, 0, stream>>>(rh, rl, WhT, WlT, qh, ql, kh, kl, vT);
  k_attn   <<<1024, 512, 0, stream>>>(edge, mask, We, qh, ql, kh, kl, vT, part_o, part_md);
  k_combine<<<8192, 256, 0, stream>>>(part_o, part_md, AO);
  k_out    <<<256,  256, 0, stream>>>(AO, WoT, xin, out);
}

// Round 3
// 227.087 us; speedup vs baseline: 1.9323x; 1.9323x over previous
//
#include <hip/hip_runtime.h>

// Problem constants
#define BB 4
#define NN 1024
#define FF 512
#define HH 8
#define DD 64
#define EE 16

typedef unsigned short u16;
typedef __attribute__((ext_vector_type(8))) short     bf16x8;
typedef __attribute__((ext_vector_type(8))) unsigned short u16x8;
typedef __attribute__((ext_vector_type(4))) float     f32x4;

#define MFMA(a,b,c) __builtin_amdgcn_mfma_f32_16x16x32_bf16((a),(b),(c),0,0,0)

static __device__ __forceinline__ u16 f2bf(float f){
  unsigned u = __float_as_uint(f);
  unsigned r = (u + 0x7FFFu + ((u >> 16) & 1u)) >> 16;   // RNE
  return (u16)r;
}
static __device__ __forceinline__ float bf2f(u16 h){
  return __uint_as_float(((unsigned)h) << 16);
}
static __device__ __forceinline__ void gld16(const void* g, void* l){
  __builtin_amdgcn_global_load_lds((const __attribute__((address_space(1))) unsigned int*)g,
                                   (__attribute__((address_space(3))) unsigned int*)l, 16, 0, 0);
}

// ---------------------------------------------------------------------------
// K0: transpose + hi/lo-split weights.
__global__ __launch_bounds__(256) void k_wsplit(
    const float* __restrict__ Wq, const float* __restrict__ Wk,
    const float* __restrict__ Wv, const float* __restrict__ Wo,
    u16* __restrict__ WhT, u16* __restrict__ WlT, u16* __restrict__ WoT){
  __shared__ float tile[32][33];
  int bid = blockIdx.x, t = threadIdx.x;
  int isA = bid < 768;
  int tb  = isA ? bid : bid - 768;
  int nct = isA ? 48 : 16;
  int ct = tb % nct, ft = tb / nct;
  int c0 = ct * 32, f0 = ft * 32;
  #pragma unroll
  for (int r4 = 0; r4 < 4; r4++){
    int fl = (t >> 5) * 4 + r4, cl = t & 31;
    int f = f0 + fl, c = c0 + cl;
    float v;
    if (isA){
      const float* W = (c < 512) ? Wq : ((c < 1024) ? Wk : Wv);
      v = W[f * 512 + (c & 511)];
    } else {
      v = Wo[f * 512 + c];
    }
    tile[fl][cl] = v;
  }
  __syncthreads();
  #pragma unroll
  for (int r4 = 0; r4 < 4; r4++){
    int cl = (t >> 5) * 4 + r4, fl = t & 31;
    float v = tile[fl][cl];
    int c = c0 + cl, f = f0 + fl;
    if (isA){
      u16 hi = f2bf(v);
      WhT[c * 512 + f] = hi;
      WlT[c * 512 + f] = f2bf(v - bf2f(hi));
    } else {
      WoT[c * 512 + f] = f2bf(v);
    }
  }
}

// ---------------------------------------------------------------------------
// K1: LayerNorm (fp32) -> r split into hi/lo bf16. One wave per row.
__global__ __launch_bounds__(256) void k_ln(
    const float* __restrict__ x, const float* __restrict__ gamma,
    const float* __restrict__ beta, u16* __restrict__ rh, u16* __restrict__ rl){
  int row  = blockIdx.x * 4 + (threadIdx.x >> 6);
  int lane = threadIdx.x & 63;
  const float* px = x + (size_t)row * 512 + lane * 8;
  float4 a = *(const float4*)px;
  float4 b = *(const float4*)(px + 4);
  float v[8] = {a.x,a.y,a.z,a.w,b.x,b.y,b.z,b.w};
  float s = 0.f, q = 0.f;
  #pragma unroll
  for (int j = 0; j < 8; j++){ s += v[j]; q += v[j]*v[j]; }
  #pragma unroll
  for (int m = 1; m < 64; m <<= 1){ s += __shfl_xor(s, m, 64); q += __shfl_xor(q, m, 64); }
  float mean = s * (1.f/512.f);
  float var  = q * (1.f/512.f) - mean * mean;
  float rstd = rsqrtf(var + 1e-5f);
  float4 ga = *(const float4*)(gamma + lane*8);
  float4 gb = *(const float4*)(gamma + lane*8 + 4);
  float4 b0 = *(const float4*)(beta  + lane*8);
  float4 b1 = *(const float4*)(beta  + lane*8 + 4);
  float gs[8] = {ga.x,ga.y,ga.z,ga.w,gb.x,gb.y,gb.z,gb.w};
  float bs[8] = {b0.x,b0.y,b0.z,b0.w,b1.x,b1.y,b1.z,b1.w};
  u16x8 hv, lv;
  #pragma unroll
  for (int j = 0; j < 8; j++){
    float r = (v[j] - mean) * rstd * gs[j] + bs[j];
    u16 hi = f2bf(r);
    hv[j] = hi;
    lv[j] = f2bf(r - bf2f(hi));
  }
  *(u16x8*)(rh + (size_t)row * 512 + lane * 8) = hv;
  *(u16x8*)(rl + (size_t)row * 512 + lane * 8) = lv;
}

// ---------------------------------------------------------------------------
// K2: QKV projection GEMM, split-3, 128x128 tile BK=32 (unchanged).
__global__ __launch_bounds__(256) void k_qkv(
    const u16* __restrict__ rh, const u16* __restrict__ rl,
    const u16* __restrict__ WhT, const u16* __restrict__ WlT,
    u16* __restrict__ qh, u16* __restrict__ ql,
    u16* __restrict__ kh, u16* __restrict__ kl, u16* __restrict__ vT){
  __shared__ u16 Ah[128*32], Al[128*32], Bh[128*32], Bl[128*32];
  int bid = blockIdx.x;
  int mt = bid & 31, nt = bid >> 5;
  int m0 = mt << 7,  n0 = nt << 7;
  int t = threadIdx.x, lane = t & 63, w = t >> 6;
  int wm = (w >> 1) << 6, wn = (w & 1) << 6;
  int fr = lane & 15, g = lane >> 4;
  f32x4 acc[4][4];
  #pragma unroll
  for (int i = 0; i < 4; i++)
    #pragma unroll
    for (int j = 0; j < 4; j++) acc[i][j] = (f32x4){0.f,0.f,0.f,0.f};

  for (int k0 = 0; k0 < 512; k0 += 32){
    #pragma unroll
    for (int q = 0; q < 2; q++){
      int c = ((q << 2) + w) * 64 + lane;
      int row = c >> 2, part = c & 3;
      int ldso = ((q << 2) + w) * 512;
      gld16(rh  + (size_t)(m0+row)*512 + k0 + part*8, &Ah[ldso]);
      gld16(rl  + (size_t)(m0+row)*512 + k0 + part*8, &Al[ldso]);
      gld16(WhT + (size_t)(n0+row)*512 + k0 + part*8, &Bh[ldso]);
      gld16(WlT + (size_t)(n0+row)*512 + k0 + part*8, &Bl[ldso]);
    }
    __syncthreads();
    bf16x8 a_h[4], a_l[4], b_h[4], b_l[4];
    #pragma unroll
    for (int mi = 0; mi < 4; mi++){
      int off = (wm + mi*16 + fr)*32 + g*8;
      a_h[mi] = *(const bf16x8*)&Ah[off];
      a_l[mi] = *(const bf16x8*)&Al[off];
    }
    #pragma unroll
    for (int ni = 0; ni < 4; ni++){
      int off = (wn + ni*16 + fr)*32 + g*8;
      b_h[ni] = *(const bf16x8*)&Bh[off];
      b_l[ni] = *(const bf16x8*)&Bl[off];
    }
    #pragma unroll
    for (int mi = 0; mi < 4; mi++)
      #pragma unroll
      for (int ni = 0; ni < 4; ni++){
        acc[mi][ni] = MFMA(a_h[mi], b_h[ni], acc[mi][ni]);
        acc[mi][ni] = MFMA(a_h[mi], b_l[ni], acc[mi][ni]);
        acc[mi][ni] = MFMA(a_l[mi], b_h[ni], acc[mi][ni]);
      }
    __syncthreads();
  }
  #pragma unroll
  for (int mi = 0; mi < 4; mi++)
    #pragma unroll
    for (int ni = 0; ni < 4; ni++)
      #pragma unroll
      for (int r = 0; r < 4; r++){
        int gm = m0 + wm + mi*16 + g*4 + r;
        int gc = n0 + wn + ni*16 + fr;
        float vv = acc[mi][ni][r];
        int b = gm >> 10, i = gm & 1023;
        int mat = gc >> 9, h = (gc >> 6) & 7, d = gc & 63;
        size_t idx = ((size_t)((b << 3) + h) * 1024 + i) * 64 + d;
        if (mat == 0){
          u16 hi = f2bf(vv); qh[idx] = hi; ql[idx] = f2bf(vv - bf2f(hi));
        } else if (mat == 1){
          u16 hi = f2bf(vv); kh[idx] = hi; kl[idx] = f2bf(vv - bf2f(hi));
        } else {
          vT[((size_t)((b << 3) + h) * 64 + d) * 1024 + i] = f2bf(vv);
        }
      }
}

// ---------------------------------------------------------------------------
// K3: fused attention, j-split 4-way. 1024 blocks = (b, i-tile of 16, s).
// NOTE: plain __launch_bounds__(512) — the (512,6) variant forced VGPR=40 and
// spilled ~900 MB of scratch traffic (round-2 post-mortem).
__global__ __launch_bounds__(512) void k_attn(
    const float* __restrict__ edge, const float* __restrict__ mask,
    const float* __restrict__ We,
    const u16* __restrict__ qh, const u16* __restrict__ ql,
    const u16* __restrict__ kh, const u16* __restrict__ kl,
    const u16* __restrict__ vT, u16* __restrict__ part_o,
    float2* __restrict__ part_md){
  __shared__ float We_s[128];                 // [e][h]
  __shared__ float bias_s[8][16*33];          // [h][i*33+j]
  __shared__ float mask_s[16*33];             // [i*33+j]
  __shared__ u16   pm_s[8][16*40];            // per-wave [i][40] bf16

  int bid = blockIdx.x;
  int s  = bid & 3;
  int i0 = ((bid >> 2) & 63) << 4;
  int b  = bid >> 8;
  int t = threadIdx.x, lane = t & 63, w = t >> 6;   // w = head
  int fr = lane & 15, g = lane >> 4;
  if (t < 128) We_s[t] = We[t];

  // Q fragments (rows i0..i0+15, all 64 d), hi/lo
  size_t qb = ((size_t)((b << 3) + w) * 1024 + i0 + fr) * 64 + g * 8;
  bf16x8 qfh0 = *(const bf16x8*)(qh + qb);
  bf16x8 qfh1 = *(const bf16x8*)(qh + qb + 32);
  bf16x8 qfl0 = *(const bf16x8*)(ql + qb);
  bf16x8 qfl1 = *(const bf16x8*)(ql + qb + 32);

  f32x4 oacc[4];
  #pragma unroll
  for (int vf = 0; vf < 4; vf++) oacc[vf] = (f32x4){0.f,0.f,0.f,0.f};
  float mrun[4], den[4];
  #pragma unroll
  for (int r = 0; r < 4; r++){ mrun[r] = -3e38f; den[r] = 0.f; }

  int pi = t >> 5, pj = t & 31;               // this thread's (i,j) pair for bias
  const float* ebase = edge + ((size_t)(b*1024 + i0 + pi) * 1024 + s*256 + pj) * 16;
  const float* mbase = mask + (size_t)(b*1024 + i0 + pi) * 1024 + s*256 + pj;
  __syncthreads();

  // prologue: edge+mask for tile 0 of this split
  float4 e0 = *(const float4*)(ebase);
  float4 e1 = *(const float4*)(ebase + 4);
  float4 e2 = *(const float4*)(ebase + 8);
  float4 e3 = *(const float4*)(ebase + 12);
  float  mval = *mbase;

  #pragma unroll 1
  for (int jt = 0; jt < 8; jt++){
    int j0 = s*256 + (jt << 5);
    float ef[16] = {e0.x,e0.y,e0.z,e0.w, e1.x,e1.y,e1.z,e1.w,
                    e2.x,e2.y,e2.z,e2.w, e3.x,e3.y,e3.z,e3.w};
    float bias[8] = {0.f,0.f,0.f,0.f,0.f,0.f,0.f,0.f};
    #pragma unroll
    for (int e = 0; e < 16; e++){
      float ev = ef[e];
      #pragma unroll
      for (int h = 0; h < 8; h++) bias[h] += ev * We_s[e*8 + h];
    }
    #pragma unroll
    for (int h = 0; h < 8; h++) bias_s[h][pi*33 + pj] = bias[h];
    mask_s[pi*33 + pj] = mval;
    __syncthreads();

    // prefetch next tile's edge (drains at end-of-loop barrier, overlapped)
    if (jt < 7){
      const float* ep = ebase + (size_t)((jt + 1) << 5) * 16;
      e0 = *(const float4*)(ep);
      e1 = *(const float4*)(ep + 4);
      e2 = *(const float4*)(ep + 8);
      e3 = *(const float4*)(ep + 12);
      mval = mbase[(jt + 1) << 5];
    }

    // K fragments for this head (j0..j0+31, hi/lo)
    size_t kb0 = ((size_t)((b << 3) + w) * 1024 + j0 + fr) * 64 + g * 8;
    size_t kb1 = kb0 + 16 * 64;
    bf16x8 kfh00 = *(const bf16x8*)(kh + kb0);
    bf16x8 kfh01 = *(const bf16x8*)(kh + kb0 + 32);
    bf16x8 kfh10 = *(const bf16x8*)(kh + kb1);
    bf16x8 kfh11 = *(const bf16x8*)(kh + kb1 + 32);
    bf16x8 kfl00 = *(const bf16x8*)(kl + kb0);
    bf16x8 kfl01 = *(const bf16x8*)(kl + kb0 + 32);
    bf16x8 kfl10 = *(const bf16x8*)(kl + kb1);
    bf16x8 kfl11 = *(const bf16x8*)(kl + kb1 + 32);

    f32x4 lg0 = (f32x4){0.f,0.f,0.f,0.f};
    f32x4 lg1 = (f32x4){0.f,0.f,0.f,0.f};
    // interleave the two independent accumulator chains
    lg0 = MFMA(qfh0, kfh00, lg0); lg1 = MFMA(qfh0, kfh10, lg1);
    lg0 = MFMA(qfh1, kfh01, lg0); lg1 = MFMA(qfh1, kfh11, lg1);
    lg0 = MFMA(qfh0, kfl00, lg0); lg1 = MFMA(qfh0, kfl10, lg1);
    lg0 = MFMA(qfh1, kfl01, lg0); lg1 = MFMA(qfh1, kfl11, lg1);
    lg0 = MFMA(qfl0, kfh00, lg0); lg1 = MFMA(qfl0, kfh10, lg1);
    lg0 = MFMA(qfl1, kfh01, lg0); lg1 = MFMA(qfl1, kfh11, lg1);

    float tm[4];
    #pragma unroll
    for (int r = 0; r < 4; r++){
      int row = g*4 + r;
      lg0[r] += bias_s[w][row*33 + fr];
      lg1[r] += bias_s[w][row*33 + 16 + fr];
      tm[r] = fmaxf(lg0[r], lg1[r]);
    }
    #pragma unroll
    for (int mk = 1; mk < 16; mk <<= 1){
      #pragma unroll
      for (int r = 0; r < 4; r++) tm[r] = fmaxf(tm[r], __shfl_xor(tm[r], mk, 16));
    }
    float p0[4], p1[4], scl[4], ps[4];
    #pragma unroll
    for (int r = 0; r < 4; r++){
      float nm = fmaxf(mrun[r], tm[r]);
      scl[r] = exp2f((mrun[r] - nm) * 1.44269504089f);
      mrun[r] = nm;
      p0[r] = exp2f((lg0[r] - nm) * 1.44269504089f);
      p1[r] = exp2f((lg1[r] - nm) * 1.44269504089f);
      ps[r] = p0[r] + p1[r];
    }
    #pragma unroll
    for (int mk = 1; mk < 16; mk <<= 1){
      #pragma unroll
      for (int r = 0; r < 4; r++) ps[r] += __shfl_xor(ps[r], mk, 16);
    }
    #pragma unroll
    for (int r = 0; r < 4; r++) den[r] = den[r] * scl[r] + ps[r];
    #pragma unroll
    for (int vf = 0; vf < 4; vf++)
      #pragma unroll
      for (int r = 0; r < 4; r++) oacc[vf][r] *= scl[r];

    // masked P -> bf16 -> LDS (C-layout scatter), then A-frag read
    #pragma unroll
    for (int r = 0; r < 4; r++){
      int row = g*4 + r;
      pm_s[w][row*40 + fr]      = f2bf(p0[r] * mask_s[row*33 + fr]);
      pm_s[w][row*40 + 16 + fr] = f2bf(p1[r] * mask_s[row*33 + 16 + fr]);
    }
    asm volatile("s_waitcnt lgkmcnt(0)" ::: "memory");
    bf16x8 pa = *(const bf16x8*)&pm_s[w][fr*40 + g*8];
    #pragma unroll
    for (int vf = 0; vf < 4; vf++){
      const u16* vp = vT + ((size_t)((b << 3) + w) * 64 + vf*16 + fr) * 1024 + j0 + g*8;
      bf16x8 vfr = *(const bf16x8*)vp;
      oacc[vf] = MFMA(pa, vfr, oacc[vf]);
    }
    __syncthreads();
  }

  // partial store: o/den as bf16, (m, den) fp32
  float id[4];
  #pragma unroll
  for (int r = 0; r < 4; r++) id[r] = 1.0f / den[r];
  int bh = (b << 3) + w;
  #pragma unroll
  for (int vf = 0; vf < 4; vf++)
    #pragma unroll
    for (int r = 0; r < 4; r++){
      int row = g*4 + r;
      part_o[((size_t)((s*32 + bh) * 1024) + i0 + row) * 64 + vf*16 + fr] =
          f2bf(oacc[vf][r] * id[r]);
    }
  if (fr == 0){
    #pragma unroll
    for (int r = 0; r < 4; r++){
      int row = g*4 + r;
      part_md[(size_t)(s*32 + bh) * 1024 + i0 + row] = make_float2(mrun[r], den[r]);
    }
  }
}

// ---------------------------------------------------------------------------
// K4: combine the 4 j-split partials -> AO bf16 [b,i][h*64+d].
__global__ __launch_bounds__(256) void k_combine(
    const u16* __restrict__ part_o, const float2* __restrict__ part_md,
    u16* __restrict__ AO){
  int wg   = blockIdx.x * 4 + (threadIdx.x >> 6);   // row id 0..32767
  int lane = threadIdx.x & 63;
  int bh = wg >> 10, i = wg & 1023;
  int b = bh >> 3, h = bh & 7;
  float2 md[4];
  float M = -3e38f;
  #pragma unroll
  for (int s = 0; s < 4; s++){
    md[s] = part_md[(size_t)(s*32 + bh) * 1024 + i];
    M = fmaxf(M, md[s].x);
  }
  float wsum = 0.f, o = 0.f;
  #pragma unroll
  for (int s = 0; s < 4; s++){
    float wq = md[s].y * exp2f((md[s].x - M) * 1.44269504089f);
    wsum += wq;
    o += wq * bf2f(part_o[((size_t)((s*32 + bh) * 1024) + i) * 64 + lane]);
  }
  AO[((size_t)(b*1024 + i)) * 512 + h*64 + lane] = f2bf(o * 0.125f / wsum);
}

// ---------------------------------------------------------------------------
// K5: out = AO @ Wo + residual. Single-pass bf16, 64x128 tile, BK=32.
__global__ __launch_bounds__(256) void k_out(
    const u16* __restrict__ AO, const u16* __restrict__ WoT,
    const float* __restrict__ x, float* __restrict__ out){
  __shared__ u16 As[64*32], Bs[128*32];
  int bid = blockIdx.x;
  int mt = bid & 63, nt = bid >> 6;
  int m0 = mt << 6, n0 = nt << 7;
  int t = threadIdx.x, lane = t & 63, w = t >> 6;
  int wm = (w >> 1) << 5, wn = (w & 1) << 6;
  int fr = lane & 15, g = lane >> 4;
  f32x4 acc[2][4];
  #pragma unroll
  for (int i = 0; i < 2; i++)
    #pragma unroll
    for (int j = 0; j < 4; j++) acc[i][j] = (f32x4){0.f,0.f,0.f,0.f};

  for (int k0 = 0; k0 < 512; k0 += 32){
    {
      int row = t >> 2, part = t & 3;
      gld16(AO + (size_t)(m0+row)*512 + k0 + part*8, &As[w*512]);
    }
    #pragma unroll
    for (int q = 0; q < 2; q++){
      int c = ((q << 2) + w) * 64 + lane;
      int row = c >> 2, part = c & 3;
      gld16(WoT + (size_t)(n0+row)*512 + k0 + part*8, &Bs[((q<<2)+w)*512]);
    }
    __syncthreads();
    bf16x8 af[2], bf_[4];
    #pragma unroll
    for (int mi = 0; mi < 2; mi++) af[mi]  = *(const bf16x8*)&As[(wm + mi*16 + fr)*32 + g*8];
    #pragma unroll
    for (int ni = 0; ni < 4; ni++) bf_[ni] = *(const bf16x8*)&Bs[(wn + ni*16 + fr)*32 + g*8];
    #pragma unroll
    for (int mi = 0; mi < 2; mi++)
      #pragma unroll
      for (int ni = 0; ni < 4; ni++)
        acc[mi][ni] = MFMA(af[mi], bf_[ni], acc[mi][ni]);
    __syncthreads();
  }
  #pragma unroll
  for (int mi = 0; mi < 2; mi++)
    #pragma unroll
    for (int ni = 0; ni < 4; ni++)
      #pragma unroll
      for (int r = 0; r < 4; r++){
        size_t gm = m0 + wm + mi*16 + g*4 + r;
        size_t gn = n0 + wn + ni*16 + fr;
        out[gm*512 + gn] = acc[mi][ni][r] + x[gm*512 + gn];
      }
}

// ---------------------------------------------------------------------------
extern "C" void kernel_launch(void* const* d_in, const int* in_sizes, int n_in,
                              void* d_out, int out_size, void* d_ws, size_t ws_size,
                              hipStream_t stream){
  const float* xin   = (const float*)d_in[0];
  const float* edge  = (const float*)d_in[1];
  const float* mask  = (const float*)d_in[2];
  const float* gamma = (const float*)d_in[3];
  const float* beta  = (const float*)d_in[4];
  const float* Wq    = (const float*)d_in[5];
  const float* Wk    = (const float*)d_in[6];
  const float* Wv    = (const float*)d_in[7];
  const float* We    = (const float*)d_in[8];
  const float* Wo    = (const float*)d_in[9];
  float* out = (float*)d_out;

  u16* p   = (u16*)d_ws;
  u16* WoT = p;                 p += 512*512;      // live until k_out
  u16* qh  = p;                 p += 2097152;
  u16* ql  = p;                 p += 2097152;
  u16* kh  = p;                 p += 2097152;
  u16* kl  = p;                 p += 2097152;
  u16* vT  = p;                 p += 2097152;
  u16* AO  = p;                 p += 2097152;
  // union region: {rh, rl, WhT, WlT} (dead after k_qkv) vs {part_o, part_md}
  u16* U   = p;
  u16* rh  = U;
  u16* rl  = U + 2097152;
  u16* WhT = U + 4194304;
  u16* WlT = U + 4194304 + 786432;
  u16* part_o = U;                                  // 4*32768*64 u16
  float2* part_md = (float2*)(U + 8388608);         // 4*32768 float2

  k_wsplit <<<1024, 256, 0, stream>>>(Wq, Wk, Wv, Wo, WhT, WlT, WoT);
  k_ln     <<<1024, 256, 0, stream>>>(xin, gamma, beta, rh, rl);
  k_qkv    <<<384,  256, 0, stream>>>(rh, rl, WhT, WlT, qh, ql, kh, kl, vT);
  k_attn   <<<1024, 512, 0, stream>>>(edge, mask, We, qh, ql, kh, kl, vT, part_o, part_md);
  k_combine<<<8192, 256, 0, stream>>>(part_o, part_md, AO);
  k_out    <<<256,  256, 0, stream>>>(AO, WoT, xin, out);
}

// Round 4
// 220.029 us; speedup vs baseline: 1.9943x; 1.0321x over previous
//
#include <hip/hip_runtime.h>

// Problem constants
#define BB 4
#define NN 1024
#define FF 512
#define HH 8
#define DD 64
#define EE 16

typedef unsigned short u16;
typedef __attribute__((ext_vector_type(8))) short     bf16x8;
typedef __attribute__((ext_vector_type(8))) unsigned short u16x8;
typedef __attribute__((ext_vector_type(4))) float     f32x4;

#define MFMA(a,b,c) __builtin_amdgcn_mfma_f32_16x16x32_bf16((a),(b),(c),0,0,0)

static __device__ __forceinline__ u16 f2bf(float f){
  unsigned u = __float_as_uint(f);
  unsigned r = (u + 0x7FFFu + ((u >> 16) & 1u)) >> 16;   // RNE
  return (u16)r;
}
static __device__ __forceinline__ float bf2f(u16 h){
  return __uint_as_float(((unsigned)h) << 16);
}
static __device__ __forceinline__ void gld16(const void* g, void* l){
  __builtin_amdgcn_global_load_lds((const __attribute__((address_space(1))) unsigned int*)g,
                                   (__attribute__((address_space(3))) unsigned int*)l, 16, 0, 0);
}

// ---------------------------------------------------------------------------
// K0: transpose + hi/lo-split weights.
__global__ __launch_bounds__(256) void k_wsplit(
    const float* __restrict__ Wq, const float* __restrict__ Wk,
    const float* __restrict__ Wv, const float* __restrict__ Wo,
    u16* __restrict__ WhT, u16* __restrict__ WlT, u16* __restrict__ WoT){
  __shared__ float tile[32][33];
  int bid = blockIdx.x, t = threadIdx.x;
  int isA = bid < 768;
  int tb  = isA ? bid : bid - 768;
  int nct = isA ? 48 : 16;
  int ct = tb % nct, ft = tb / nct;
  int c0 = ct * 32, f0 = ft * 32;
  #pragma unroll
  for (int r4 = 0; r4 < 4; r4++){
    int fl = (t >> 5) * 4 + r4, cl = t & 31;
    int f = f0 + fl, c = c0 + cl;
    float v;
    if (isA){
      const float* W = (c < 512) ? Wq : ((c < 1024) ? Wk : Wv);
      v = W[f * 512 + (c & 511)];
    } else {
      v = Wo[f * 512 + c];
    }
    tile[fl][cl] = v;
  }
  __syncthreads();
  #pragma unroll
  for (int r4 = 0; r4 < 4; r4++){
    int cl = (t >> 5) * 4 + r4, fl = t & 31;
    float v = tile[fl][cl];
    int c = c0 + cl, f = f0 + fl;
    if (isA){
      u16 hi = f2bf(v);
      WhT[c * 512 + f] = hi;
      WlT[c * 512 + f] = f2bf(v - bf2f(hi));
    } else {
      WoT[c * 512 + f] = f2bf(v);
    }
  }
}

// ---------------------------------------------------------------------------
// K1: LayerNorm (fp32) -> r split into hi/lo bf16. One wave per row.
__global__ __launch_bounds__(256) void k_ln(
    const float* __restrict__ x, const float* __restrict__ gamma,
    const float* __restrict__ beta, u16* __restrict__ rh, u16* __restrict__ rl){
  int row  = blockIdx.x * 4 + (threadIdx.x >> 6);
  int lane = threadIdx.x & 63;
  const float* px = x + (size_t)row * 512 + lane * 8;
  float4 a = *(const float4*)px;
  float4 b = *(const float4*)(px + 4);
  float v[8] = {a.x,a.y,a.z,a.w,b.x,b.y,b.z,b.w};
  float s = 0.f, q = 0.f;
  #pragma unroll
  for (int j = 0; j < 8; j++){ s += v[j]; q += v[j]*v[j]; }
  #pragma unroll
  for (int m = 1; m < 64; m <<= 1){ s += __shfl_xor(s, m, 64); q += __shfl_xor(q, m, 64); }
  float mean = s * (1.f/512.f);
  float var  = q * (1.f/512.f) - mean * mean;
  float rstd = rsqrtf(var + 1e-5f);
  float4 ga = *(const float4*)(gamma + lane*8);
  float4 gb = *(const float4*)(gamma + lane*8 + 4);
  float4 b0 = *(const float4*)(beta  + lane*8);
  float4 b1 = *(const float4*)(beta  + lane*8 + 4);
  float gs[8] = {ga.x,ga.y,ga.z,ga.w,gb.x,gb.y,gb.z,gb.w};
  float bs[8] = {b0.x,b0.y,b0.z,b0.w,b1.x,b1.y,b1.z,b1.w};
  u16x8 hv, lv;
  #pragma unroll
  for (int j = 0; j < 8; j++){
    float r = (v[j] - mean) * rstd * gs[j] + bs[j];
    u16 hi = f2bf(r);
    hv[j] = hi;
    lv[j] = f2bf(r - bf2f(hi));
  }
  *(u16x8*)(rh + (size_t)row * 512 + lane * 8) = hv;
  *(u16x8*)(rl + (size_t)row * 512 + lane * 8) = lv;
}

// ---------------------------------------------------------------------------
// K2: QKV projection GEMM, split-3, 128x128 tile BK=32 (unchanged).
__global__ __launch_bounds__(256) void k_qkv(
    const u16* __restrict__ rh, const u16* __restrict__ rl,
    const u16* __restrict__ WhT, const u16* __restrict__ WlT,
    u16* __restrict__ qh, u16* __restrict__ ql,
    u16* __restrict__ kh, u16* __restrict__ kl, u16* __restrict__ vT){
  __shared__ u16 Ah[128*32], Al[128*32], Bh[128*32], Bl[128*32];
  int bid = blockIdx.x;
  int mt = bid & 31, nt = bid >> 5;
  int m0 = mt << 7,  n0 = nt << 7;
  int t = threadIdx.x, lane = t & 63, w = t >> 6;
  int wm = (w >> 1) << 6, wn = (w & 1) << 6;
  int fr = lane & 15, g = lane >> 4;
  f32x4 acc[4][4];
  #pragma unroll
  for (int i = 0; i < 4; i++)
    #pragma unroll
    for (int j = 0; j < 4; j++) acc[i][j] = (f32x4){0.f,0.f,0.f,0.f};

  for (int k0 = 0; k0 < 512; k0 += 32){
    #pragma unroll
    for (int q = 0; q < 2; q++){
      int c = ((q << 2) + w) * 64 + lane;
      int row = c >> 2, part = c & 3;
      int ldso = ((q << 2) + w) * 512;
      gld16(rh  + (size_t)(m0+row)*512 + k0 + part*8, &Ah[ldso]);
      gld16(rl  + (size_t)(m0+row)*512 + k0 + part*8, &Al[ldso]);
      gld16(WhT + (size_t)(n0+row)*512 + k0 + part*8, &Bh[ldso]);
      gld16(WlT + (size_t)(n0+row)*512 + k0 + part*8, &Bl[ldso]);
    }
    __syncthreads();
    bf16x8 a_h[4], a_l[4], b_h[4], b_l[4];
    #pragma unroll
    for (int mi = 0; mi < 4; mi++){
      int off = (wm + mi*16 + fr)*32 + g*8;
      a_h[mi] = *(const bf16x8*)&Ah[off];
      a_l[mi] = *(const bf16x8*)&Al[off];
    }
    #pragma unroll
    for (int ni = 0; ni < 4; ni++){
      int off = (wn + ni*16 + fr)*32 + g*8;
      b_h[ni] = *(const bf16x8*)&Bh[off];
      b_l[ni] = *(const bf16x8*)&Bl[off];
    }
    #pragma unroll
    for (int mi = 0; mi < 4; mi++)
      #pragma unroll
      for (int ni = 0; ni < 4; ni++){
        acc[mi][ni] = MFMA(a_h[mi], b_h[ni], acc[mi][ni]);
        acc[mi][ni] = MFMA(a_h[mi], b_l[ni], acc[mi][ni]);
        acc[mi][ni] = MFMA(a_l[mi], b_h[ni], acc[mi][ni]);
      }
    __syncthreads();
  }
  #pragma unroll
  for (int mi = 0; mi < 4; mi++)
    #pragma unroll
    for (int ni = 0; ni < 4; ni++)
      #pragma unroll
      for (int r = 0; r < 4; r++){
        int gm = m0 + wm + mi*16 + g*4 + r;
        int gc = n0 + wn + ni*16 + fr;
        float vv = acc[mi][ni][r];
        int b = gm >> 10, i = gm & 1023;
        int mat = gc >> 9, h = (gc >> 6) & 7, d = gc & 63;
        size_t idx = ((size_t)((b << 3) + h) * 1024 + i) * 64 + d;
        if (mat == 0){
          u16 hi = f2bf(vv); qh[idx] = hi; ql[idx] = f2bf(vv - bf2f(hi));
        } else if (mat == 1){
          u16 hi = f2bf(vv); kh[idx] = hi; kl[idx] = f2bf(vv - bf2f(hi));
        } else {
          vT[((size_t)((b << 3) + h) * 64 + d) * 1024 + i] = f2bf(vv);
        }
      }
}

// ---------------------------------------------------------------------------
// K3: fused attention, pipelined single-barrier loop. 256 blocks = (b, i-tile).
// Per iter: issue K/V loads (oldest) -> sched_barrier -> issue next edge/mask
// loads (newer; K-use waits counted vmcnt, edge NOT drained) -> read bias[cur]
// -> QK MFMA + online softmax + PV -> compute bias[nxt] from edge regs (late
// use: HBM latency hidden across the body) -> ONE __syncthreads -> swap.
__global__ __launch_bounds__(512) void k_attn(
    const float* __restrict__ edge, const float* __restrict__ mask,
    const float* __restrict__ We,
    const u16* __restrict__ qh, const u16* __restrict__ ql,
    const u16* __restrict__ kh, const u16* __restrict__ kl,
    const u16* __restrict__ vT, u16* __restrict__ AO){
  __shared__ float We_s[128];                 // [e][h]
  __shared__ float bias_s[2][8][16*33];       // dbuf [h][i*33+j]
  __shared__ float mask_s[2][16*33];          // dbuf [i*33+j]
  __shared__ u16   pm_s[8][16*40];            // per-wave [i][40] bf16

  int bid = blockIdx.x;
  int b = bid >> 6, i0 = (bid & 63) << 4;
  int t = threadIdx.x, lane = t & 63, w = t >> 6;   // w = head
  int fr = lane & 15, g = lane >> 4;
  if (t < 128) We_s[t] = We[t];

  // Q fragments (rows i0..i0+15, all 64 d), hi/lo
  size_t qb = ((size_t)((b << 3) + w) * 1024 + i0 + fr) * 64 + g * 8;
  bf16x8 qfh0 = *(const bf16x8*)(qh + qb);
  bf16x8 qfh1 = *(const bf16x8*)(qh + qb + 32);
  bf16x8 qfl0 = *(const bf16x8*)(ql + qb);
  bf16x8 qfl1 = *(const bf16x8*)(ql + qb + 32);

  f32x4 oacc[4];
  #pragma unroll
  for (int vf = 0; vf < 4; vf++) oacc[vf] = (f32x4){0.f,0.f,0.f,0.f};
  float mrun[4], den[4];
  #pragma unroll
  for (int r = 0; r < 4; r++){ mrun[r] = -3e38f; den[r] = 0.f; }

  int pi = t >> 5, pj = t & 31;               // this thread's (i,j) for bias
  const float* ebase = edge + ((size_t)(b*1024 + i0 + pi) * 1024 + pj) * 16;
  const float* mbase = mask + (size_t)(b*1024 + i0 + pi) * 1024 + pj;

  // prologue: tile-0 edge+mask, bias into buf 0
  float4 e0 = *(const float4*)(ebase);
  float4 e1 = *(const float4*)(ebase + 4);
  float4 e2 = *(const float4*)(ebase + 8);
  float4 e3 = *(const float4*)(ebase + 12);
  float  mval = *mbase;
  __syncthreads();                            // We_s visible
  {
    float ef[16] = {e0.x,e0.y,e0.z,e0.w, e1.x,e1.y,e1.z,e1.w,
                    e2.x,e2.y,e2.z,e2.w, e3.x,e3.y,e3.z,e3.w};
    float bias[8] = {0.f,0.f,0.f,0.f,0.f,0.f,0.f,0.f};
    #pragma unroll
    for (int e = 0; e < 16; e++){
      float ev = ef[e];
      #pragma unroll
      for (int h = 0; h < 8; h++) bias[h] += ev * We_s[e*8 + h];
    }
    #pragma unroll
    for (int h = 0; h < 8; h++) bias_s[0][h][pi*33 + pj] = bias[h];
    mask_s[0][pi*33 + pj] = mval;
  }
  __syncthreads();                            // bias_s[0] ready
  int cur = 0;

  #pragma unroll 1
  for (int jt = 0; jt < 32; jt++){
    int j0 = jt << 5;

    // (1) issue K fragment loads (oldest VMEM this iter)
    size_t kb0 = ((size_t)((b << 3) + w) * 1024 + j0 + fr) * 64 + g * 8;
    size_t kb1 = kb0 + 16 * 64;
    bf16x8 kfh00 = *(const bf16x8*)(kh + kb0);
    bf16x8 kfh01 = *(const bf16x8*)(kh + kb0 + 32);
    bf16x8 kfh10 = *(const bf16x8*)(kh + kb1);
    bf16x8 kfh11 = *(const bf16x8*)(kh + kb1 + 32);
    bf16x8 kfl00 = *(const bf16x8*)(kl + kb0);
    bf16x8 kfl01 = *(const bf16x8*)(kl + kb0 + 32);
    bf16x8 kfl10 = *(const bf16x8*)(kl + kb1);
    bf16x8 kfl11 = *(const bf16x8*)(kl + kb1 + 32);
    // V fragments (consumed after softmax -> latency hidden)
    bf16x8 vfr[4];
    #pragma unroll
    for (int vf = 0; vf < 4; vf++)
      vfr[vf] = *(const bf16x8*)(vT + ((size_t)((b << 3) + w) * 64 + vf*16 + fr) * 1024 + j0 + g*8);
    __builtin_amdgcn_sched_barrier(0);

    // (2) issue NEXT tile's edge+mask loads (newer than K/V -> not waited by K-use)
    if (jt < 31){
      const float* ep = ebase + (size_t)(j0 + 32) * 16;
      e0 = *(const float4*)(ep);
      e1 = *(const float4*)(ep + 4);
      e2 = *(const float4*)(ep + 8);
      e3 = *(const float4*)(ep + 12);
      mval = mbase[j0 + 32];
    }
    __builtin_amdgcn_sched_barrier(0);

    // (3) read bias/mask for current tile from LDS
    float bs0[4], bs1[4], ms0[4], ms1[4];
    #pragma unroll
    for (int r = 0; r < 4; r++){
      int row = g*4 + r;
      bs0[r] = bias_s[cur][w][row*33 + fr];
      bs1[r] = bias_s[cur][w][row*33 + 16 + fr];
      ms0[r] = mask_s[cur][row*33 + fr];
      ms1[r] = mask_s[cur][row*33 + 16 + fr];
    }

    // (4) QK^T (split-3), bias add, online softmax
    f32x4 lg0 = (f32x4){0.f,0.f,0.f,0.f};
    f32x4 lg1 = (f32x4){0.f,0.f,0.f,0.f};
    lg0 = MFMA(qfh0, kfh00, lg0); lg1 = MFMA(qfh0, kfh10, lg1);
    lg0 = MFMA(qfh1, kfh01, lg0); lg1 = MFMA(qfh1, kfh11, lg1);
    lg0 = MFMA(qfh0, kfl00, lg0); lg1 = MFMA(qfh0, kfl10, lg1);
    lg0 = MFMA(qfh1, kfl01, lg0); lg1 = MFMA(qfh1, kfl11, lg1);
    lg0 = MFMA(qfl0, kfh00, lg0); lg1 = MFMA(qfl0, kfh10, lg1);
    lg0 = MFMA(qfl1, kfh01, lg0); lg1 = MFMA(qfl1, kfh11, lg1);

    float tm[4];
    #pragma unroll
    for (int r = 0; r < 4; r++){
      lg0[r] += bs0[r];
      lg1[r] += bs1[r];
      tm[r] = fmaxf(lg0[r], lg1[r]);
    }
    #pragma unroll
    for (int mk = 1; mk < 16; mk <<= 1){
      #pragma unroll
      for (int r = 0; r < 4; r++) tm[r] = fmaxf(tm[r], __shfl_xor(tm[r], mk, 16));
    }
    float p0[4], p1[4], scl[4], ps[4];
    #pragma unroll
    for (int r = 0; r < 4; r++){
      float nm = fmaxf(mrun[r], tm[r]);
      scl[r] = exp2f((mrun[r] - nm) * 1.44269504089f);
      mrun[r] = nm;
      p0[r] = exp2f((lg0[r] - nm) * 1.44269504089f);
      p1[r] = exp2f((lg1[r] - nm) * 1.44269504089f);
      ps[r] = p0[r] + p1[r];
    }
    #pragma unroll
    for (int mk = 1; mk < 16; mk <<= 1){
      #pragma unroll
      for (int r = 0; r < 4; r++) ps[r] += __shfl_xor(ps[r], mk, 16);
    }
    #pragma unroll
    for (int r = 0; r < 4; r++) den[r] = den[r] * scl[r] + ps[r];
    #pragma unroll
    for (int vf = 0; vf < 4; vf++)
      #pragma unroll
      for (int r = 0; r < 4; r++) oacc[vf][r] *= scl[r];

    // (5) masked P -> bf16 -> per-wave LDS scatter, A-frag read, PV MFMA
    #pragma unroll
    for (int r = 0; r < 4; r++){
      int row = g*4 + r;
      pm_s[w][row*40 + fr]      = f2bf(p0[r] * ms0[r]);
      pm_s[w][row*40 + 16 + fr] = f2bf(p1[r] * ms1[r]);
    }
    asm volatile("s_waitcnt lgkmcnt(0)" ::: "memory");
    bf16x8 pa = *(const bf16x8*)&pm_s[w][fr*40 + g*8];
    #pragma unroll
    for (int vf = 0; vf < 4; vf++)
      oacc[vf] = MFMA(pa, vfr[vf], oacc[vf]);

    // (6) compute next tile's bias from edge regs (late use of HBM loads)
    if (jt < 31){
      float ef[16] = {e0.x,e0.y,e0.z,e0.w, e1.x,e1.y,e1.z,e1.w,
                      e2.x,e2.y,e2.z,e2.w, e3.x,e3.y,e3.z,e3.w};
      float bias[8] = {0.f,0.f,0.f,0.f,0.f,0.f,0.f,0.f};
      #pragma unroll
      for (int e = 0; e < 16; e++){
        float ev = ef[e];
        #pragma unroll
        for (int h = 0; h < 8; h++) bias[h] += ev * We_s[e*8 + h];
      }
      int nxt = cur ^ 1;
      #pragma unroll
      for (int h = 0; h < 8; h++) bias_s[nxt][h][pi*33 + pj] = bias[h];
      mask_s[nxt][pi*33 + pj] = mval;
    }
    __syncthreads();                          // ONE barrier per iter
    cur ^= 1;
  }

  float id[4];
  #pragma unroll
  for (int r = 0; r < 4; r++) id[r] = 0.125f / den[r];   // fold in 1/sqrt(D)
  #pragma unroll
  for (int vf = 0; vf < 4; vf++)
    #pragma unroll
    for (int r = 0; r < 4; r++){
      int row = g*4 + r, v = vf*16 + fr;
      AO[((size_t)(b*1024 + i0 + row)) * 512 + w*64 + v] = f2bf(oacc[vf][r] * id[r]);
    }
}

// ---------------------------------------------------------------------------
// K5: out = AO @ Wo + residual. Single-pass bf16, 64x128 tile, BK=32.
__global__ __launch_bounds__(256) void k_out(
    const u16* __restrict__ AO, const u16* __restrict__ WoT,
    const float* __restrict__ x, float* __restrict__ out){
  __shared__ u16 As[64*32], Bs[128*32];
  int bid = blockIdx.x;
  int mt = bid & 63, nt = bid >> 6;
  int m0 = mt << 6, n0 = nt << 7;
  int t = threadIdx.x, lane = t & 63, w = t >> 6;
  int wm = (w >> 1) << 5, wn = (w & 1) << 6;
  int fr = lane & 15, g = lane >> 4;
  f32x4 acc[2][4];
  #pragma unroll
  for (int i = 0; i < 2; i++)
    #pragma unroll
    for (int j = 0; j < 4; j++) acc[i][j] = (f32x4){0.f,0.f,0.f,0.f};

  for (int k0 = 0; k0 < 512; k0 += 32){
    {
      int row = t >> 2, part = t & 3;
      gld16(AO + (size_t)(m0+row)*512 + k0 + part*8, &As[w*512]);
    }
    #pragma unroll
    for (int q = 0; q < 2; q++){
      int c = ((q << 2) + w) * 64 + lane;
      int row = c >> 2, part = c & 3;
      gld16(WoT + (size_t)(n0+row)*512 + k0 + part*8, &Bs[((q<<2)+w)*512]);
    }
    __syncthreads();
    bf16x8 af[2], bf_[4];
    #pragma unroll
    for (int mi = 0; mi < 2; mi++) af[mi]  = *(const bf16x8*)&As[(wm + mi*16 + fr)*32 + g*8];
    #pragma unroll
    for (int ni = 0; ni < 4; ni++) bf_[ni] = *(const bf16x8*)&Bs[(wn + ni*16 + fr)*32 + g*8];
    #pragma unroll
    for (int mi = 0; mi < 2; mi++)
      #pragma unroll
      for (int ni = 0; ni < 4; ni++)
        acc[mi][ni] = MFMA(af[mi], bf_[ni], acc[mi][ni]);
    __syncthreads();
  }
  #pragma unroll
  for (int mi = 0; mi < 2; mi++)
    #pragma unroll
    for (int ni = 0; ni < 4; ni++)
      #pragma unroll
      for (int r = 0; r < 4; r++){
        size_t gm = m0 + wm + mi*16 + g*4 + r;
        size_t gn = n0 + wn + ni*16 + fr;
        out[gm*512 + gn] = acc[mi][ni][r] + x[gm*512 + gn];
      }
}

// ---------------------------------------------------------------------------
extern "C" void kernel_launch(void* const* d_in, const int* in_sizes, int n_in,
                              void* d_out, int out_size, void* d_ws, size_t ws_size,
                              hipStream_t stream){
  const float* xin   = (const float*)d_in[0];
  const float* edge  = (const float*)d_in[1];
  const float* mask  = (const float*)d_in[2];
  const float* gamma = (const float*)d_in[3];
  const float* beta  = (const float*)d_in[4];
  const float* Wq    = (const float*)d_in[5];
  const float* Wk    = (const float*)d_in[6];
  const float* Wv    = (const float*)d_in[7];
  const float* We    = (const float*)d_in[8];
  const float* Wo    = (const float*)d_in[9];
  float* out = (float*)d_out;

  u16* p   = (u16*)d_ws;
  u16* WhT = p;                 p += 1536*512;
  u16* WlT = p;                 p += 1536*512;
  u16* WoT = p;                 p += 512*512;
  u16* rh  = p;                 p += 4096*512;
  u16* rl  = p;                 p += 4096*512;
  u16* qh  = p;                 p += 2097152;
  u16* ql  = p;                 p += 2097152;
  u16* kh  = p;                 p += 2097152;
  u16* kl  = p;                 p += 2097152;
  u16* vT  = p;                 p += 2097152;
  u16* AO  = p;                 p += 2097152;

  k_wsplit<<<1024, 256, 0, stream>>>(Wq, Wk, Wv, Wo, WhT, WlT, WoT);
  k_ln    <<<1024, 256, 0, stream>>>(xin, gamma, beta, rh, rl);
  k_qkv   <<<384,  256, 0, stream>>>(rh, rl, WhT, WlT, qh, ql, kh, kl, vT);
  k_attn  <<<256,  512, 0, stream>>>(edge, mask, We, qh, ql, kh, kl, vT, AO);
  k_out   <<<256,  256, 0, stream>>>(AO, WoT, xin, out);
}

// Round 5
// 193.942 us; speedup vs baseline: 2.2625x; 1.1345x over previous
//
#include <hip/hip_runtime.h>

// Problem constants
#define BB 4
#define NN 1024
#define FF 512
#define HH 8
#define DD 64
#define EE 16

typedef unsigned short u16;
typedef _Float16 f16;
typedef __attribute__((ext_vector_type(8))) _Float16 f16x8;
typedef __attribute__((ext_vector_type(4))) float     f32x4;

#define MFMAH(a,b,c) __builtin_amdgcn_mfma_f32_16x16x32_f16((a),(b),(c),0,0,0)

static __device__ __forceinline__ void gld16(const void* g, void* l){
  __builtin_amdgcn_global_load_lds((const __attribute__((address_space(1))) unsigned int*)g,
                                   (__attribute__((address_space(3))) unsigned int*)l, 16, 0, 0);
}

// ---------------------------------------------------------------------------
// K0: transpose weights -> f16. [Wq|Wk|Wv] (512f x 1536c) -> WT [c][f] f16;
// Wo (512f x 512c) -> WoT [c][f] f16.
__global__ __launch_bounds__(256) void k_wsplit(
    const float* __restrict__ Wq, const float* __restrict__ Wk,
    const float* __restrict__ Wv, const float* __restrict__ Wo,
    f16* __restrict__ WT, f16* __restrict__ WoT){
  __shared__ float tile[32][33];
  int bid = blockIdx.x, t = threadIdx.x;
  int isA = bid < 768;
  int tb  = isA ? bid : bid - 768;
  int nct = isA ? 48 : 16;
  int ct = tb % nct, ft = tb / nct;
  int c0 = ct * 32, f0 = ft * 32;
  #pragma unroll
  for (int r4 = 0; r4 < 4; r4++){
    int fl = (t >> 5) * 4 + r4, cl = t & 31;
    int f = f0 + fl, c = c0 + cl;
    float v;
    if (isA){
      const float* W = (c < 512) ? Wq : ((c < 1024) ? Wk : Wv);
      v = W[f * 512 + (c & 511)];
    } else {
      v = Wo[f * 512 + c];
    }
    tile[fl][cl] = v;
  }
  __syncthreads();
  #pragma unroll
  for (int r4 = 0; r4 < 4; r4++){
    int cl = (t >> 5) * 4 + r4, fl = t & 31;
    float v = tile[fl][cl];
    int c = c0 + cl, f = f0 + fl;
    if (isA) WT[c * 512 + f]  = (f16)v;
    else     WoT[c * 512 + f] = (f16)v;
  }
}

// ---------------------------------------------------------------------------
// K1: LayerNorm (fp32) -> r as f16. One wave per row.
__global__ __launch_bounds__(256) void k_ln(
    const float* __restrict__ x, const float* __restrict__ gamma,
    const float* __restrict__ beta, f16* __restrict__ rf){
  int row  = blockIdx.x * 4 + (threadIdx.x >> 6);
  int lane = threadIdx.x & 63;
  const float* px = x + (size_t)row * 512 + lane * 8;
  float4 a = *(const float4*)px;
  float4 b = *(const float4*)(px + 4);
  float v[8] = {a.x,a.y,a.z,a.w,b.x,b.y,b.z,b.w};
  float s = 0.f, q = 0.f;
  #pragma unroll
  for (int j = 0; j < 8; j++){ s += v[j]; q += v[j]*v[j]; }
  #pragma unroll
  for (int m = 1; m < 64; m <<= 1){ s += __shfl_xor(s, m, 64); q += __shfl_xor(q, m, 64); }
  float mean = s * (1.f/512.f);
  float var  = q * (1.f/512.f) - mean * mean;
  float rstd = rsqrtf(var + 1e-5f);
  float4 ga = *(const float4*)(gamma + lane*8);
  float4 gb = *(const float4*)(gamma + lane*8 + 4);
  float4 b0 = *(const float4*)(beta  + lane*8);
  float4 b1 = *(const float4*)(beta  + lane*8 + 4);
  float gs[8] = {ga.x,ga.y,ga.z,ga.w,gb.x,gb.y,gb.z,gb.w};
  float bs[8] = {b0.x,b0.y,b0.z,b0.w,b1.x,b1.y,b1.z,b1.w};
  f16x8 hv;
  #pragma unroll
  for (int j = 0; j < 8; j++){
    float r = (v[j] - mean) * rstd * gs[j] + bs[j];
    hv[j] = (f16)r;
  }
  *(f16x8*)(rf + (size_t)row * 512 + lane * 8) = hv;
}

// ---------------------------------------------------------------------------
// K2: QKV projection GEMM, f16 single-pass, 128x128 tile BK=32.
// Epilogue: q,k -> [b][h][n][64] f16; v -> transposed [b][h][64][n] f16.
__global__ __launch_bounds__(256) void k_qkv(
    const f16* __restrict__ rf, const f16* __restrict__ WT,
    f16* __restrict__ qf, f16* __restrict__ kf, f16* __restrict__ vT){
  __shared__ f16 As[128*32], Bs[128*32];
  int bid = blockIdx.x;
  int mt = bid & 31, nt = bid >> 5;       // 32 m-tiles x 12 n-tiles
  int m0 = mt << 7,  n0 = nt << 7;
  int t = threadIdx.x, lane = t & 63, w = t >> 6;
  int wm = (w >> 1) << 6, wn = (w & 1) << 6;
  int fr = lane & 15, g = lane >> 4;
  f32x4 acc[4][4];
  #pragma unroll
  for (int i = 0; i < 4; i++)
    #pragma unroll
    for (int j = 0; j < 4; j++) acc[i][j] = (f32x4){0.f,0.f,0.f,0.f};

  for (int k0 = 0; k0 < 512; k0 += 32){
    #pragma unroll
    for (int q = 0; q < 2; q++){
      int c = ((q << 2) + w) * 64 + lane;   // chunk id, 16B each
      int row = c >> 2, part = c & 3;
      int ldso = ((q << 2) + w) * 512;      // f16 units, wave-uniform
      gld16(rf + (size_t)(m0+row)*512 + k0 + part*8, &As[ldso]);
      gld16(WT + (size_t)(n0+row)*512 + k0 + part*8, &Bs[ldso]);
    }
    __syncthreads();
    f16x8 a[4], b[4];
    #pragma unroll
    for (int mi = 0; mi < 4; mi++) a[mi] = *(const f16x8*)&As[(wm + mi*16 + fr)*32 + g*8];
    #pragma unroll
    for (int ni = 0; ni < 4; ni++) b[ni] = *(const f16x8*)&Bs[(wn + ni*16 + fr)*32 + g*8];
    #pragma unroll
    for (int mi = 0; mi < 4; mi++)
      #pragma unroll
      for (int ni = 0; ni < 4; ni++)
        acc[mi][ni] = MFMAH(a[mi], b[ni], acc[mi][ni]);
    __syncthreads();
  }
  #pragma unroll
  for (int mi = 0; mi < 4; mi++)
    #pragma unroll
    for (int ni = 0; ni < 4; ni++)
      #pragma unroll
      for (int r = 0; r < 4; r++){
        int gm = m0 + wm + mi*16 + g*4 + r;
        int gc = n0 + wn + ni*16 + fr;
        float vv = acc[mi][ni][r];
        int b = gm >> 10, i = gm & 1023;
        int mat = gc >> 9, h = (gc >> 6) & 7, d = gc & 63;
        size_t idx = ((size_t)((b << 3) + h) * 1024 + i) * 64 + d;
        if      (mat == 0) qf[idx] = (f16)vv;
        else if (mat == 1) kf[idx] = (f16)vv;
        else vT[((size_t)((b << 3) + h) * 64 + d) * 1024 + i] = (f16)vv;
      }
}

// ---------------------------------------------------------------------------
// K3: fused attention, f16, j-split 4-way, single-barrier dbuf pipeline.
// 1024 blocks = (b, i-tile of 16, s). 512 thr = 8 waves = 8 heads.
__global__ __launch_bounds__(512) void k_attn(
    const float* __restrict__ edge, const float* __restrict__ mask,
    const float* __restrict__ We,
    const f16* __restrict__ qf, const f16* __restrict__ kf,
    const f16* __restrict__ vT, f16* __restrict__ part_o,
    float2* __restrict__ part_md){
  __shared__ float We_s[128];                 // [e][h]
  __shared__ float bias_s[2][8][16*33];       // dbuf [h][i*33+j]
  __shared__ float mask_s[2][16*33];          // dbuf [i*33+j]
  __shared__ f16   pm_s[8][16*40];            // per-wave [i][40]

  int bid = blockIdx.x;
  int s  = bid & 3;
  int i0 = ((bid >> 2) & 63) << 4;
  int b  = bid >> 8;
  int t = threadIdx.x, lane = t & 63, w = t >> 6;   // w = head
  int fr = lane & 15, g = lane >> 4;
  if (t < 128) We_s[t] = We[t];

  // Q fragments (rows i0..i0+15, all 64 d)
  size_t qb = ((size_t)((b << 3) + w) * 1024 + i0 + fr) * 64 + g * 8;
  f16x8 qf0 = *(const f16x8*)(qf + qb);
  f16x8 qf1 = *(const f16x8*)(qf + qb + 32);

  f32x4 oacc[4];
  #pragma unroll
  for (int vf = 0; vf < 4; vf++) oacc[vf] = (f32x4){0.f,0.f,0.f,0.f};
  float mrun[4], den[4];
  #pragma unroll
  for (int r = 0; r < 4; r++){ mrun[r] = -3e38f; den[r] = 0.f; }

  int pi = t >> 5, pj = t & 31;               // this thread's (i,j) for bias
  const float* ebase = edge + ((size_t)(b*1024 + i0 + pi) * 1024 + s*256 + pj) * 16;
  const float* mbase = mask + (size_t)(b*1024 + i0 + pi) * 1024 + s*256 + pj;

  // prologue: tile-0 edge+mask, bias into buf 0
  float4 e0 = *(const float4*)(ebase);
  float4 e1 = *(const float4*)(ebase + 4);
  float4 e2 = *(const float4*)(ebase + 8);
  float4 e3 = *(const float4*)(ebase + 12);
  float  mval = *mbase;
  __syncthreads();                            // We_s visible
  {
    float ef[16] = {e0.x,e0.y,e0.z,e0.w, e1.x,e1.y,e1.z,e1.w,
                    e2.x,e2.y,e2.z,e2.w, e3.x,e3.y,e3.z,e3.w};
    float bias[8] = {0.f,0.f,0.f,0.f,0.f,0.f,0.f,0.f};
    #pragma unroll
    for (int e = 0; e < 16; e++){
      float ev = ef[e];
      #pragma unroll
      for (int h = 0; h < 8; h++) bias[h] += ev * We_s[e*8 + h];
    }
    #pragma unroll
    for (int h = 0; h < 8; h++) bias_s[0][h][pi*33 + pj] = bias[h];
    mask_s[0][pi*33 + pj] = mval;
  }
  __syncthreads();                            // bias_s[0] ready
  int cur = 0;

  #pragma unroll 1
  for (int jt = 0; jt < 8; jt++){
    int j0 = s*256 + (jt << 5);

    // (1) issue K/V fragment loads (oldest VMEM this iter)
    size_t kb0 = ((size_t)((b << 3) + w) * 1024 + j0 + fr) * 64 + g * 8;
    size_t kb1 = kb0 + 16 * 64;
    f16x8 kf00 = *(const f16x8*)(kf + kb0);
    f16x8 kf01 = *(const f16x8*)(kf + kb0 + 32);
    f16x8 kf10 = *(const f16x8*)(kf + kb1);
    f16x8 kf11 = *(const f16x8*)(kf + kb1 + 32);
    f16x8 vfr[4];
    #pragma unroll
    for (int vf = 0; vf < 4; vf++)
      vfr[vf] = *(const f16x8*)(vT + ((size_t)((b << 3) + w) * 64 + vf*16 + fr) * 1024 + j0 + g*8);
    __builtin_amdgcn_sched_barrier(0);

    // (2) issue NEXT tile's edge+mask loads (newer -> K-use doesn't wait them)
    if (jt < 7){
      const float* ep = ebase + (size_t)((jt + 1) << 5) * 16;
      e0 = *(const float4*)(ep);
      e1 = *(const float4*)(ep + 4);
      e2 = *(const float4*)(ep + 8);
      e3 = *(const float4*)(ep + 12);
      mval = mbase[(jt + 1) << 5];
    }
    __builtin_amdgcn_sched_barrier(0);

    // (3) bias/mask for current tile from LDS
    float bs0[4], bs1[4], ms0[4], ms1[4];
    #pragma unroll
    for (int r = 0; r < 4; r++){
      int row = g*4 + r;
      bs0[r] = bias_s[cur][w][row*33 + fr];
      bs1[r] = bias_s[cur][w][row*33 + 16 + fr];
      ms0[r] = mask_s[cur][row*33 + fr];
      ms1[r] = mask_s[cur][row*33 + 16 + fr];
    }

    // (4) QK^T f16, bias add, online softmax
    f32x4 lg0 = (f32x4){0.f,0.f,0.f,0.f};
    f32x4 lg1 = (f32x4){0.f,0.f,0.f,0.f};
    lg0 = MFMAH(qf0, kf00, lg0); lg1 = MFMAH(qf0, kf10, lg1);
    lg0 = MFMAH(qf1, kf01, lg0); lg1 = MFMAH(qf1, kf11, lg1);

    float tm[4];
    #pragma unroll
    for (int r = 0; r < 4; r++){
      lg0[r] += bs0[r];
      lg1[r] += bs1[r];
      tm[r] = fmaxf(lg0[r], lg1[r]);
    }
    #pragma unroll
    for (int mk = 1; mk < 16; mk <<= 1){
      #pragma unroll
      for (int r = 0; r < 4; r++) tm[r] = fmaxf(tm[r], __shfl_xor(tm[r], mk, 16));
    }
    float p0[4], p1[4], scl[4], ps[4];
    #pragma unroll
    for (int r = 0; r < 4; r++){
      float nm = fmaxf(mrun[r], tm[r]);
      scl[r] = exp2f((mrun[r] - nm) * 1.44269504089f);
      mrun[r] = nm;
      p0[r] = exp2f((lg0[r] - nm) * 1.44269504089f);
      p1[r] = exp2f((lg1[r] - nm) * 1.44269504089f);
      ps[r] = p0[r] + p1[r];
    }
    #pragma unroll
    for (int mk = 1; mk < 16; mk <<= 1){
      #pragma unroll
      for (int r = 0; r < 4; r++) ps[r] += __shfl_xor(ps[r], mk, 16);
    }
    #pragma unroll
    for (int r = 0; r < 4; r++) den[r] = den[r] * scl[r] + ps[r];
    #pragma unroll
    for (int vf = 0; vf < 4; vf++)
      #pragma unroll
      for (int r = 0; r < 4; r++) oacc[vf][r] *= scl[r];

    // (5) masked P -> f16 -> per-wave LDS scatter, A-frag read, PV MFMA
    #pragma unroll
    for (int r = 0; r < 4; r++){
      int row = g*4 + r;
      pm_s[w][row*40 + fr]      = (f16)(p0[r] * ms0[r]);
      pm_s[w][row*40 + 16 + fr] = (f16)(p1[r] * ms1[r]);
    }
    asm volatile("s_waitcnt lgkmcnt(0)" ::: "memory");
    f16x8 pa = *(const f16x8*)&pm_s[w][fr*40 + g*8];
    #pragma unroll
    for (int vf = 0; vf < 4; vf++)
      oacc[vf] = MFMAH(pa, vfr[vf], oacc[vf]);

    // (6) next tile's bias from edge regs (late use of HBM loads)
    if (jt < 7){
      float ef[16] = {e0.x,e0.y,e0.z,e0.w, e1.x,e1.y,e1.z,e1.w,
                      e2.x,e2.y,e2.z,e2.w, e3.x,e3.y,e3.z,e3.w};
      float bias[8] = {0.f,0.f,0.f,0.f,0.f,0.f,0.f,0.f};
      #pragma unroll
      for (int e = 0; e < 16; e++){
        float ev = ef[e];
        #pragma unroll
        for (int h = 0; h < 8; h++) bias[h] += ev * We_s[e*8 + h];
      }
      int nxt = cur ^ 1;
      #pragma unroll
      for (int h = 0; h < 8; h++) bias_s[nxt][h][pi*33 + pj] = bias[h];
      mask_s[nxt][pi*33 + pj] = mval;
    }
    __syncthreads();                          // ONE barrier per iter
    cur ^= 1;
  }

  // partial store: o/den as f16, (m, den) fp32
  float id[4];
  #pragma unroll
  for (int r = 0; r < 4; r++) id[r] = 1.0f / den[r];
  int bh = (b << 3) + w;
  #pragma unroll
  for (int vf = 0; vf < 4; vf++)
    #pragma unroll
    for (int r = 0; r < 4; r++){
      int row = g*4 + r;
      part_o[((size_t)((s*32 + bh) * 1024) + i0 + row) * 64 + vf*16 + fr] =
          (f16)(oacc[vf][r] * id[r]);
    }
  if (fr == 0){
    #pragma unroll
    for (int r = 0; r < 4; r++){
      int row = g*4 + r;
      part_md[(size_t)(s*32 + bh) * 1024 + i0 + row] = make_float2(mrun[r], den[r]);
    }
  }
}

// ---------------------------------------------------------------------------
// K4: combine the 4 j-split partials -> AO f16 [b,i][h*64+d].
__global__ __launch_bounds__(256) void k_combine(
    const f16* __restrict__ part_o, const float2* __restrict__ part_md,
    f16* __restrict__ AO){
  int wg   = blockIdx.x * 4 + (threadIdx.x >> 6);   // row id 0..32767
  int lane = threadIdx.x & 63;
  int bh = wg >> 10, i = wg & 1023;
  int b = bh >> 3, h = bh & 7;
  float2 md[4];
  float M = -3e38f;
  #pragma unroll
  for (int s = 0; s < 4; s++){
    md[s] = part_md[(size_t)(s*32 + bh) * 1024 + i];
    M = fmaxf(M, md[s].x);
  }
  float wsum = 0.f, o = 0.f;
  #pragma unroll
  for (int s = 0; s < 4; s++){
    float wq = md[s].y * exp2f((md[s].x - M) * 1.44269504089f);
    wsum += wq;
    o += wq * (float)part_o[((size_t)((s*32 + bh) * 1024) + i) * 64 + lane];
  }
  AO[((size_t)(b*1024 + i)) * 512 + h*64 + lane] = (f16)(o * 0.125f / wsum);
}

// ---------------------------------------------------------------------------
// K5: out = AO @ Wo + residual. f16 single-pass, 64x128 tile, BK=32.
__global__ __launch_bounds__(256) void k_out(
    const f16* __restrict__ AO, const f16* __restrict__ WoT,
    const float* __restrict__ x, float* __restrict__ out){
  __shared__ f16 As[64*32], Bs[128*32];
  int bid = blockIdx.x;
  int mt = bid & 63, nt = bid >> 6;     // 64 x 4
  int m0 = mt << 6, n0 = nt << 7;
  int t = threadIdx.x, lane = t & 63, w = t >> 6;
  int wm = (w >> 1) << 5, wn = (w & 1) << 6;
  int fr = lane & 15, g = lane >> 4;
  f32x4 acc[2][4];
  #pragma unroll
  for (int i = 0; i < 2; i++)
    #pragma unroll
    for (int j = 0; j < 4; j++) acc[i][j] = (f32x4){0.f,0.f,0.f,0.f};

  for (int k0 = 0; k0 < 512; k0 += 32){
    {
      int row = t >> 2, part = t & 3;
      gld16(AO + (size_t)(m0+row)*512 + k0 + part*8, &As[w*512]);
    }
    #pragma unroll
    for (int q = 0; q < 2; q++){
      int c = ((q << 2) + w) * 64 + lane;
      int row = c >> 2, part = c & 3;
      gld16(WoT + (size_t)(n0+row)*512 + k0 + part*8, &Bs[((q<<2)+w)*512]);
    }
    __syncthreads();
    f16x8 af[2], bf_[4];
    #pragma unroll
    for (int mi = 0; mi < 2; mi++) af[mi]  = *(const f16x8*)&As[(wm + mi*16 + fr)*32 + g*8];
    #pragma unroll
    for (int ni = 0; ni < 4; ni++) bf_[ni] = *(const f16x8*)&Bs[(wn + ni*16 + fr)*32 + g*8];
    #pragma unroll
    for (int mi = 0; mi < 2; mi++)
      #pragma unroll
      for (int ni = 0; ni < 4; ni++)
        acc[mi][ni] = MFMAH(af[mi], bf_[ni], acc[mi][ni]);
    __syncthreads();
  }
  #pragma unroll
  for (int mi = 0; mi < 2; mi++)
    #pragma unroll
    for (int ni = 0; ni < 4; ni++)
      #pragma unroll
      for (int r = 0; r < 4; r++){
        size_t gm = m0 + wm + mi*16 + g*4 + r;
        size_t gn = n0 + wn + ni*16 + fr;
        out[gm*512 + gn] = acc[mi][ni][r] + x[gm*512 + gn];
      }
}

// ---------------------------------------------------------------------------
extern "C" void kernel_launch(void* const* d_in, const int* in_sizes, int n_in,
                              void* d_out, int out_size, void* d_ws, size_t ws_size,
                              hipStream_t stream){
  const float* xin   = (const float*)d_in[0];
  const float* edge  = (const float*)d_in[1];
  const float* mask  = (const float*)d_in[2];
  const float* gamma = (const float*)d_in[3];
  const float* beta  = (const float*)d_in[4];
  const float* Wq    = (const float*)d_in[5];
  const float* Wk    = (const float*)d_in[6];
  const float* Wv    = (const float*)d_in[7];
  const float* We    = (const float*)d_in[8];
  const float* Wo    = (const float*)d_in[9];
  float* out = (float*)d_out;

  f16* p   = (f16*)d_ws;
  f16* WT  = p;                 p += 1536*512;
  f16* WoT = p;                 p += 512*512;
  f16* rf  = p;                 p += 4096*512;
  f16* qf  = p;                 p += 2097152;
  f16* kf  = p;                 p += 2097152;
  f16* vT  = p;                 p += 2097152;
  f16* AO  = p;                 p += 2097152;
  f16* part_o = p;              p += 8388608;       // 4*32*1024*64
  float2* part_md = (float2*)p;                     // 131072 float2

  k_wsplit <<<1024, 256, 0, stream>>>(Wq, Wk, Wv, Wo, WT, WoT);
  k_ln     <<<1024, 256, 0, stream>>>(xin, gamma, beta, rf);
  k_qkv    <<<384,  256, 0, stream>>>(rf, WT, qf, kf, vT);
  k_attn   <<<1024, 512, 0, stream>>>(edge, mask, We, qf, kf, vT, part_o, part_md);
  k_combine<<<8192, 256, 0, stream>>>(part_o, part_md, AO);
  k_out    <<<256,  256, 0, stream>>>(AO, WoT, xin, out);
}